// Round 2
// baseline (111.642 us; speedup 1.0000x reference)
//
#include <hip/hip_runtime.h>
#include <math.h>

// Strategy: force = MLP(|dr|) is piecewise-linear in the scalar edge length.
// Build a dense fp32 lookup table of force(d) on [0, R], then the edge pass
// is gather + lerp + scatter-add.
//
// Round-2 change: the scatter-add no longer uses device-scope atomics (which
// execute at the memory side on multi-XCD CDNA4 — measured 50 MB write
// traffic, 18.6 Gatomic/s ceiling). Instead: 8 partial outputs, one per
// physical XCD; blocks read HW_REG_XCC_ID and use WORKGROUP-scope atomics,
// which execute in the local (per-XCD) L2 where the 800 KB partial is
// resident. A final pass sums the 8 partials (+ -gamma*v). Dispatch-boundary
// L2 writeback guarantees cross-kernel visibility.

#define M_TAB 8192
#define EPSF 1e-12f
#define N_OUT 200000
#define NXCD 8

#define WS_TABLE_OFF 256
#define WS_PART_OFF 65536
#define WS_NEEDED (WS_PART_OFF + (size_t)NXCD * N_OUT * 4)

// K0a: zero the 8 partial copies + wsu[0].
__global__ __launch_bounds__(256) void k0_zero(float4* __restrict__ part4,
                                               unsigned* __restrict__ wsu,
                                               int n4) {
  int i = blockIdx.x * blockDim.x + threadIdx.x;
  if (i == 0) wsu[0] = 0u;
  if (i < n4) part4[i] = make_float4(0.f, 0.f, 0.f, 0.f);
}

// K0b (fallback path): out[i] = -gamma * v[i]; zero wsu.
__global__ __launch_bounds__(256) void k0_init(const float* __restrict__ v,
                                               const float* __restrict__ gamma,
                                               float* __restrict__ out,
                                               unsigned* __restrict__ wsu,
                                               int n) {
  int i = blockIdx.x * blockDim.x + threadIdx.x;
  if (i == 0) wsu[0] = 0u;
  if (i < n) out[i] = -gamma[0] * v[i];
}

// K1: max over nodes of ||x_i||^2 -> wsu[0] (uint-ordered atomicMax, valid
// since values are non-negative).
__global__ __launch_bounds__(256) void k1_maxnorm(const float* __restrict__ x,
                                                  unsigned* __restrict__ wsu,
                                                  int n) {
  __shared__ float red[256];
  int tid = threadIdx.x;
  float m = 0.f;
  for (int i = blockIdx.x * blockDim.x + tid; i < n;
       i += gridDim.x * blockDim.x) {
    float2 p = ((const float2*)x)[i];
    m = fmaxf(m, fmaf(p.x, p.x, p.y * p.y));
  }
  red[tid] = m;
  __syncthreads();
  for (int s = 128; s > 0; s >>= 1) {
    if (tid < s) red[tid] = fmaxf(red[tid], red[tid + s]);
    __syncthreads();
  }
  if (tid == 0) atomicMax(wsu, __float_as_uint(red[0]));
}

// K2: build table[i] = MLP(i * R/(M_TAB-1)) in exact fp32.
__global__ __launch_bounds__(128) void k2_table(
    const float* __restrict__ W0, const float* __restrict__ b0,
    const float* __restrict__ W1, const float* __restrict__ b1,
    const float* __restrict__ W2, const float* __restrict__ b2,
    const float* __restrict__ W3, const float* __restrict__ b3,
    const unsigned* __restrict__ wsu, float* __restrict__ table) {
  __shared__ float bufA[128 * 8];
  __shared__ float bufB[128 * 8];
  const int j = threadIdx.x;
  const float R = 2.f * sqrtf(__uint_as_float(wsu[0]));
  const float step = R / (float)(M_TAB - 1);
  const int base = blockIdx.x * 8;

  // L0: 1 -> 128, ReLU
  {
    float w = W0[j], b = b0[j];
#pragma unroll
    for (int p = 0; p < 8; ++p)
      bufA[j * 8 + p] = fmaxf(fmaf((float)(base + p) * step, w, b), 0.f);
  }
  __syncthreads();

  float acc[8];
  // L1: 128 -> 128, ReLU  (reads bufA, writes bufB)
  {
    float b = b1[j];
#pragma unroll
    for (int p = 0; p < 8; ++p) acc[p] = b;
#pragma unroll 8
    for (int k = 0; k < 128; ++k) {
      float w = W1[k * 128 + j];
      float4 h0 = *(const float4*)&bufA[k * 8];
      float4 h1 = *(const float4*)&bufA[k * 8 + 4];
      acc[0] = fmaf(h0.x, w, acc[0]);
      acc[1] = fmaf(h0.y, w, acc[1]);
      acc[2] = fmaf(h0.z, w, acc[2]);
      acc[3] = fmaf(h0.w, w, acc[3]);
      acc[4] = fmaf(h1.x, w, acc[4]);
      acc[5] = fmaf(h1.y, w, acc[5]);
      acc[6] = fmaf(h1.z, w, acc[6]);
      acc[7] = fmaf(h1.w, w, acc[7]);
    }
#pragma unroll
    for (int p = 0; p < 8; ++p) bufB[j * 8 + p] = fmaxf(acc[p], 0.f);
  }
  __syncthreads();

  // L2: 128 -> 128, ReLU (reads bufB), then * W3[j], stash partials in bufA.
  {
    float b = b2[j];
#pragma unroll
    for (int p = 0; p < 8; ++p) acc[p] = b;
#pragma unroll 8
    for (int k = 0; k < 128; ++k) {
      float w = W2[k * 128 + j];
      float4 h0 = *(const float4*)&bufB[k * 8];
      float4 h1 = *(const float4*)&bufB[k * 8 + 4];
      acc[0] = fmaf(h0.x, w, acc[0]);
      acc[1] = fmaf(h0.y, w, acc[1]);
      acc[2] = fmaf(h0.z, w, acc[2]);
      acc[3] = fmaf(h0.w, w, acc[3]);
      acc[4] = fmaf(h1.x, w, acc[4]);
      acc[5] = fmaf(h1.y, w, acc[5]);
      acc[6] = fmaf(h1.z, w, acc[6]);
      acc[7] = fmaf(h1.w, w, acc[7]);
    }
    float w3 = W3[j];
#pragma unroll
    for (int p = 0; p < 8; ++p) bufA[j * 8 + p] = fmaxf(acc[p], 0.f) * w3;
  }
  __syncthreads();

  for (int s = 64; s > 0; s >>= 1) {
    if (j < s) {
#pragma unroll
      for (int p = 0; p < 8; ++p) bufA[j * 8 + p] += bufA[(j + s) * 8 + p];
    }
    __syncthreads();
  }
  if (j < 8) table[base + j] = bufA[j] + b3[0];
}

__device__ __forceinline__ void edge_msg(const float* __restrict__ x,
                                         const float* __restrict__ table,
                                         float R, int s, int t, float& vx,
                                         float& vy) {
  float2 xs = ((const float2*)x)[s];
  float2 xt = ((const float2*)x)[t];
  float dx = xt.x - xs.x, dy = xt.y - xs.y;
  float d = sqrtf(fmaf(dx, dx, dy * dy));
  float step = R / (float)(M_TAB - 1);
  float u = d / step;
  u = fminf(u, (float)(M_TAB - 1));
  int i0 = (int)u;
  if (i0 > M_TAB - 2) i0 = M_TAB - 2;
  float frac = u - (float)i0;
  float f0 = table[i0], f1 = table[i0 + 1];
  float f = fmaf(frac, f1 - f0, f0);
  float sc = f / fmaxf(d, EPSF);
  vx = sc * dx;
  vy = sc * dy;
}

// K3 (fast path): per-edge message -> L2-local atomic into this XCD's
// partial copy. WORKGROUP scope => global_atomic_add_f32 without the
// write-through-to-memory-side policy bit => executes in the local L2,
// which is shared by every CU on this XCD => correct for the per-XCD copy.
__global__ __launch_bounds__(256) void k3_part(
    const float* __restrict__ x, const int* __restrict__ src,
    const int* __restrict__ dst, const float* __restrict__ table,
    const unsigned* __restrict__ wsu, float* __restrict__ partial, int E) {
  int e = blockIdx.x * blockDim.x + threadIdx.x;
  if (e >= E) return;
  unsigned xcc;
  asm volatile("s_getreg_b32 %0, hwreg(HW_REG_XCC_ID, 0, 32)" : "=s"(xcc));
  float* p = partial + (size_t)(xcc & (NXCD - 1)) * N_OUT;
  float R = 2.f * sqrtf(__uint_as_float(wsu[0]));
  int s = src[e], t = dst[e];
  float vx, vy;
  edge_msg(x, table, R, s, t, vx, vy);
  __hip_atomic_fetch_add(&p[2 * t + 0], vx, __ATOMIC_RELAXED,
                         __HIP_MEMORY_SCOPE_WORKGROUP);
  __hip_atomic_fetch_add(&p[2 * t + 1], vy, __ATOMIC_RELAXED,
                         __HIP_MEMORY_SCOPE_WORKGROUP);
}

// K3 (fallback): direct device-scope atomics into out.
__global__ __launch_bounds__(256) void k3_direct(
    const float* __restrict__ x, const int* __restrict__ src,
    const int* __restrict__ dst, const float* __restrict__ table,
    const unsigned* __restrict__ wsu, float* __restrict__ out, int E) {
  int e = blockIdx.x * blockDim.x + threadIdx.x;
  if (e >= E) return;
  float R = 2.f * sqrtf(__uint_as_float(wsu[0]));
  int s = src[e], t = dst[e];
  float vx, vy;
  edge_msg(x, table, R, s, t, vx, vy);
  atomicAdd(&out[2 * t + 0], vx);
  atomicAdd(&out[2 * t + 1], vy);
}

// K4: out = -gamma*v + sum over the 8 partial copies. float4-vectorized.
__global__ __launch_bounds__(256) void k4_finish(
    const float4* __restrict__ v4, const float* __restrict__ gamma,
    const float4* __restrict__ part4, float4* __restrict__ out4, int n4) {
  int i = blockIdx.x * blockDim.x + threadIdx.x;
  if (i >= n4) return;
  float g = -gamma[0];
  float4 a = v4[i];
  float4 acc = make_float4(g * a.x, g * a.y, g * a.z, g * a.w);
#pragma unroll
  for (int c = 0; c < NXCD; ++c) {
    float4 p = part4[(size_t)c * (N_OUT / 4) + i];
    acc.x += p.x;
    acc.y += p.y;
    acc.z += p.z;
    acc.w += p.w;
  }
  out4[i] = acc;
}

extern "C" void kernel_launch(void* const* d_in, const int* in_sizes, int n_in,
                              void* d_out, int out_size, void* d_ws,
                              size_t ws_size, hipStream_t stream) {
  const float* x = (const float*)d_in[0];
  const float* v = (const float*)d_in[1];
  const int* src = (const int*)d_in[2];
  const int* dst = (const int*)d_in[3];
  const float* gamma = (const float*)d_in[4];
  const float* W0 = (const float*)d_in[5];
  const float* b0 = (const float*)d_in[6];
  const float* W1 = (const float*)d_in[7];
  const float* b1 = (const float*)d_in[8];
  const float* W2 = (const float*)d_in[9];
  const float* b2 = (const float*)d_in[10];
  const float* W3 = (const float*)d_in[11];
  const float* b3 = (const float*)d_in[12];
  float* out = (float*)d_out;
  unsigned* wsu = (unsigned*)d_ws;
  float* table = (float*)((char*)d_ws + WS_TABLE_OFF);
  float* partial = (float*)((char*)d_ws + WS_PART_OFF);

  int n_out = out_size;           // 200000
  int n_nodes = in_sizes[0] / 2;  // 100000
  int E = in_sizes[2];            // 800000

  bool fast = (ws_size >= WS_NEEDED) && (n_out == N_OUT);

  if (fast) {
    int n4 = NXCD * N_OUT / 4;
    hipLaunchKernelGGL(k0_zero, dim3((n4 + 255) / 256), dim3(256), 0, stream,
                       (float4*)partial, wsu, n4);
  } else {
    hipLaunchKernelGGL(k0_init, dim3((n_out + 255) / 256), dim3(256), 0,
                       stream, v, gamma, out, wsu, n_out);
  }
  hipLaunchKernelGGL(k1_maxnorm, dim3(128), dim3(256), 0, stream, x, wsu,
                     n_nodes);
  hipLaunchKernelGGL(k2_table, dim3(M_TAB / 8), dim3(128), 0, stream, W0, b0,
                     W1, b1, W2, b2, W3, b3, wsu, table);
  if (fast) {
    hipLaunchKernelGGL(k3_part, dim3((E + 255) / 256), dim3(256), 0, stream, x,
                       src, dst, table, wsu, partial, E);
    hipLaunchKernelGGL(k4_finish, dim3((N_OUT / 4 + 255) / 256), dim3(256), 0,
                       stream, (const float4*)v, gamma, (const float4*)partial,
                       (float4*)out, N_OUT / 4);
  } else {
    hipLaunchKernelGGL(k3_direct, dim3((E + 255) / 256), dim3(256), 0, stream,
                       x, src, dst, table, wsu, out, E);
  }
}

// Round 3
// 101.684 us; speedup vs baseline: 1.0979x; 1.0979x over previous
//
#include <hip/hip_runtime.h>
#include <math.h>

// force = MLP(|dr|) is piecewise-linear in the scalar edge length -> build a
// dense fp32 table of force(d) on [0, R], edge pass is gather + lerp.
//
// Round-3: global fp32 atomics are memory-side-executed on gfx950 (measured:
// 18.8 G atomic/s ceiling, 32 B write traffic per atomic, scope hint has no
// effect). Eliminate them: partition nodes into ranges of 8192 (64 KB LDS of
// float2 accumulators per block). Block (r,s) streams edge-slice s, filters
// dst>>13==r, accumulates matching messages with LDS atomics, then
// plain-stores its exclusively-owned range of partial copy s. k4 sums the S
// partial copies + (-gamma*v). Zero global atomics anywhere.

#define M_TAB 8192
#define EPSF 1e-12f
#define N_OUT 200000
#define RANGE_N 8192
#define RANGE_SHIFT 13
#define S_MAX 24
#define NBM 128  // number of k1 block maxes

#define WS_BM_OFF 0
#define WS_TABLE_OFF 1024
#define WS_PART_OFF 65536

// K1: per-block max of ||x_i||^2 -> bm[blockIdx.x]. No atomics, no pre-zero.
__global__ __launch_bounds__(256) void k1_maxnorm(const float* __restrict__ x,
                                                  float* __restrict__ bm,
                                                  int n) {
  __shared__ float red[256];
  int tid = threadIdx.x;
  float m = 0.f;
  for (int i = blockIdx.x * blockDim.x + tid; i < n;
       i += gridDim.x * blockDim.x) {
    float2 p = ((const float2*)x)[i];
    m = fmaxf(m, fmaf(p.x, p.x, p.y * p.y));
  }
  red[tid] = m;
  __syncthreads();
  for (int s = 128; s > 0; s >>= 1) {
    if (tid < s) red[tid] = fmaxf(red[tid], red[tid + s]);
    __syncthreads();
  }
  if (tid == 0) bm[blockIdx.x] = red[0];
}

// K2: build table[i] = MLP(i * R/(M_TAB-1)) in exact fp32.
__global__ __launch_bounds__(128) void k2_table(
    const float* __restrict__ W0, const float* __restrict__ b0,
    const float* __restrict__ W1, const float* __restrict__ b1,
    const float* __restrict__ W2, const float* __restrict__ b2,
    const float* __restrict__ W3, const float* __restrict__ b3,
    const float* __restrict__ bm, float* __restrict__ table) {
  __shared__ float bufA[128 * 8];
  __shared__ float bufB[128 * 8];
  const int j = threadIdx.x;

  // Reduce the 128 block-maxes -> R (uniform), using bufA as scratch.
  bufA[j] = bm[j];
  __syncthreads();
  for (int st = 64; st > 0; st >>= 1) {
    if (j < st) bufA[j] = fmaxf(bufA[j], bufA[j + st]);
    __syncthreads();
  }
  const float R = fmaxf(2.f * sqrtf(bufA[0]), 1e-20f);
  __syncthreads();

  const float step = R / (float)(M_TAB - 1);
  const int base = blockIdx.x * 8;

  // L0: 1 -> 128, ReLU
  {
    float w = W0[j], b = b0[j];
#pragma unroll
    for (int p = 0; p < 8; ++p)
      bufA[j * 8 + p] = fmaxf(fmaf((float)(base + p) * step, w, b), 0.f);
  }
  __syncthreads();

  float acc[8];
  // L1: 128 -> 128, ReLU (reads bufA, writes bufB)
  {
    float b = b1[j];
#pragma unroll
    for (int p = 0; p < 8; ++p) acc[p] = b;
#pragma unroll 8
    for (int k = 0; k < 128; ++k) {
      float w = W1[k * 128 + j];
      float4 h0 = *(const float4*)&bufA[k * 8];
      float4 h1 = *(const float4*)&bufA[k * 8 + 4];
      acc[0] = fmaf(h0.x, w, acc[0]);
      acc[1] = fmaf(h0.y, w, acc[1]);
      acc[2] = fmaf(h0.z, w, acc[2]);
      acc[3] = fmaf(h0.w, w, acc[3]);
      acc[4] = fmaf(h1.x, w, acc[4]);
      acc[5] = fmaf(h1.y, w, acc[5]);
      acc[6] = fmaf(h1.z, w, acc[6]);
      acc[7] = fmaf(h1.w, w, acc[7]);
    }
#pragma unroll
    for (int p = 0; p < 8; ++p) bufB[j * 8 + p] = fmaxf(acc[p], 0.f);
  }
  __syncthreads();

  // L2: 128 -> 128, ReLU (reads bufB), * W3[j], partials into bufA.
  {
    float b = b2[j];
#pragma unroll
    for (int p = 0; p < 8; ++p) acc[p] = b;
#pragma unroll 8
    for (int k = 0; k < 128; ++k) {
      float w = W2[k * 128 + j];
      float4 h0 = *(const float4*)&bufB[k * 8];
      float4 h1 = *(const float4*)&bufB[k * 8 + 4];
      acc[0] = fmaf(h0.x, w, acc[0]);
      acc[1] = fmaf(h0.y, w, acc[1]);
      acc[2] = fmaf(h0.z, w, acc[2]);
      acc[3] = fmaf(h0.w, w, acc[3]);
      acc[4] = fmaf(h1.x, w, acc[4]);
      acc[5] = fmaf(h1.y, w, acc[5]);
      acc[6] = fmaf(h1.z, w, acc[6]);
      acc[7] = fmaf(h1.w, w, acc[7]);
    }
    float w3 = W3[j];
#pragma unroll
    for (int p = 0; p < 8; ++p) bufA[j * 8 + p] = fmaxf(acc[p], 0.f) * w3;
  }
  __syncthreads();

  for (int s = 64; s > 0; s >>= 1) {
    if (j < s) {
#pragma unroll
      for (int p = 0; p < 8; ++p) bufA[j * 8 + p] += bufA[(j + s) * 8 + p];
    }
    __syncthreads();
  }
  if (j < 8) table[base + j] = bufA[j] + b3[0];
}

__device__ __forceinline__ void edge_msg(const float* __restrict__ x,
                                         const float* __restrict__ table,
                                         float inv_step, int s, int t,
                                         float& vx, float& vy) {
  float2 xs = ((const float2*)x)[s];
  float2 xt = ((const float2*)x)[t];
  float dx = xt.x - xs.x, dy = xt.y - xs.y;
  float d = sqrtf(fmaf(dx, dx, dy * dy));
  float u = fminf(d * inv_step, (float)(M_TAB - 1));
  int i0 = (int)u;
  if (i0 > M_TAB - 2) i0 = M_TAB - 2;
  float frac = u - (float)i0;
  float f0 = table[i0], f1 = table[i0 + 1];
  float f = fmaf(frac, f1 - f0, f0);
  float sc = f / fmaxf(d, EPSF);
  vx = sc * dx;
  vy = sc * dy;
}

// K3 (fast path): block (r,s) = node-range r, edge-slice s.
// LDS float2 accumulators for 8192 nodes; plain-store to partial copy s.
__global__ __launch_bounds__(512) void k3_ranges(
    const float* __restrict__ x, const int* __restrict__ src,
    const int* __restrict__ dst, const float* __restrict__ table,
    const float* __restrict__ bm, float* __restrict__ partial, int E,
    int eper, int n_nodes) {
  __shared__ float acc[RANGE_N * 2];  // exactly 64 KB
  const int tid = threadIdx.x;
  const int r = blockIdx.x;
  const int s = blockIdx.y;

  // R from block maxes (acc[0..127] as scratch).
  if (tid < NBM) acc[tid] = bm[tid];
  __syncthreads();
  for (int st = NBM / 2; st > 0; st >>= 1) {
    if (tid < st) acc[tid] = fmaxf(acc[tid], acc[tid + st]);
    __syncthreads();
  }
  const float R = fmaxf(2.f * sqrtf(acc[0]), 1e-20f);
  const float inv_step = (float)(M_TAB - 1) / R;
  __syncthreads();

  for (int i = tid; i < RANGE_N * 2; i += 512) acc[i] = 0.f;
  __syncthreads();

  const int node0 = r << RANGE_SHIFT;
  const int e0 = s * eper;
  const int e1 = min(E, e0 + eper);

#define PROCESS(t, e)                                      \
  if (((t) >> RANGE_SHIFT) == r) {                         \
    int sidx = src[(e)];                                   \
    float vx, vy;                                          \
    edge_msg(x, table, inv_step, sidx, (t), vx, vy);       \
    int loc = ((t)-node0) * 2;                             \
    atomicAdd(&acc[loc], vx);                              \
    atomicAdd(&acc[loc + 1], vy);                          \
  }

  // Fast path: chunks of 8192 edges (512 threads x 4 int4 loads).
  int eb = e0;
  for (; eb + 8192 <= e1; eb += 8192) {
    int4 d4[4];
#pragma unroll
    for (int u = 0; u < 4; ++u)
      d4[u] = *(const int4*)(dst + eb + u * 2048 + tid * 4);
#pragma unroll
    for (int u = 0; u < 4; ++u) {
      int e = eb + u * 2048 + tid * 4;
      PROCESS(d4[u].x, e + 0);
      PROCESS(d4[u].y, e + 1);
      PROCESS(d4[u].z, e + 2);
      PROCESS(d4[u].w, e + 3);
    }
  }
  // Tail: scalar.
  for (int e = eb + tid; e < e1; e += 512) {
    int t = dst[e];
    PROCESS(t, e);
  }
#undef PROCESS
  __syncthreads();

  // Plain-store the owned range of partial copy s (float4).
  const int cnt = min(RANGE_N, n_nodes - node0) * 2;
  float4* po4 = (float4*)(partial + (size_t)s * N_OUT + (size_t)node0 * 2);
  const float4* a4 = (const float4*)acc;
  for (int i = tid; i < cnt / 4; i += 512) po4[i] = a4[i];
}

// K3 fallback: direct device-scope atomics (used only if d_ws is tiny).
__global__ __launch_bounds__(256) void k3_direct(
    const float* __restrict__ x, const int* __restrict__ src,
    const int* __restrict__ dst, const float* __restrict__ table,
    const float* __restrict__ bm, float* __restrict__ out, int E) {
  __shared__ float red[NBM];
  int tid = threadIdx.x;
  if (tid < NBM) red[tid] = bm[tid];
  __syncthreads();
  for (int st = NBM / 2; st > 0; st >>= 1) {
    if (tid < st) red[tid] = fmaxf(red[tid], red[tid + st]);
    __syncthreads();
  }
  float R = fmaxf(2.f * sqrtf(red[0]), 1e-20f);
  float inv_step = (float)(M_TAB - 1) / R;
  int e = blockIdx.x * blockDim.x + tid;
  if (e >= E) return;
  int s = src[e], t = dst[e];
  float vx, vy;
  edge_msg(x, table, inv_step, s, t, vx, vy);
  atomicAdd(&out[2 * t + 0], vx);
  atomicAdd(&out[2 * t + 1], vy);
}

// K0 (fallback only): out = -gamma*v.
__global__ __launch_bounds__(256) void k0_init(const float* __restrict__ v,
                                               const float* __restrict__ gamma,
                                               float* __restrict__ out,
                                               int n) {
  int i = blockIdx.x * blockDim.x + threadIdx.x;
  if (i < n) out[i] = -gamma[0] * v[i];
}

// K4: out = -gamma*v + sum_{s<S} partial[s]. float4-vectorized.
__global__ __launch_bounds__(256) void k4_finish(
    const float4* __restrict__ v4, const float* __restrict__ gamma,
    const float4* __restrict__ part4, float4* __restrict__ out4, int n4,
    int S) {
  int i = blockIdx.x * blockDim.x + threadIdx.x;
  if (i >= n4) return;
  float g = -gamma[0];
  float4 a = v4[i];
  float4 acc = make_float4(g * a.x, g * a.y, g * a.z, g * a.w);
  for (int c = 0; c < S; ++c) {
    float4 p = part4[(size_t)c * (N_OUT / 4) + i];
    acc.x += p.x;
    acc.y += p.y;
    acc.z += p.z;
    acc.w += p.w;
  }
  out4[i] = acc;
}

extern "C" void kernel_launch(void* const* d_in, const int* in_sizes, int n_in,
                              void* d_out, int out_size, void* d_ws,
                              size_t ws_size, hipStream_t stream) {
  const float* x = (const float*)d_in[0];
  const float* v = (const float*)d_in[1];
  const int* src = (const int*)d_in[2];
  const int* dst = (const int*)d_in[3];
  const float* gamma = (const float*)d_in[4];
  const float* W0 = (const float*)d_in[5];
  const float* b0 = (const float*)d_in[6];
  const float* W1 = (const float*)d_in[7];
  const float* b1 = (const float*)d_in[8];
  const float* W2 = (const float*)d_in[9];
  const float* b2 = (const float*)d_in[10];
  const float* W3 = (const float*)d_in[11];
  const float* b3 = (const float*)d_in[12];
  float* out = (float*)d_out;
  float* bm = (float*)((char*)d_ws + WS_BM_OFF);
  float* table = (float*)((char*)d_ws + WS_TABLE_OFF);
  float* partial = (float*)((char*)d_ws + WS_PART_OFF);

  int n_out = out_size;           // 200000
  int n_nodes = in_sizes[0] / 2;  // 100000
  int E = in_sizes[2];            // 800000

  // Choose number of edge-slices S from available workspace.
  size_t avail = ws_size > WS_PART_OFF ? ws_size - WS_PART_OFF : 0;
  int S = (int)(avail / ((size_t)N_OUT * 4));
  if (S > S_MAX) S = S_MAX;
  bool fast = (S >= 1) && (n_out == N_OUT);

  hipLaunchKernelGGL(k1_maxnorm, dim3(NBM), dim3(256), 0, stream, x, bm,
                     n_nodes);
  hipLaunchKernelGGL(k2_table, dim3(M_TAB / 8), dim3(128), 0, stream, W0, b0,
                     W1, b1, W2, b2, W3, b3, bm, table);
  if (fast) {
    int eper = ((E + S - 1) / S + 8191) & ~8191;
    int S_eff = (E + eper - 1) / eper;  // <= S
    int NR = (n_nodes + RANGE_N - 1) >> RANGE_SHIFT;
    hipLaunchKernelGGL(k3_ranges, dim3(NR, S_eff), dim3(512), 0, stream, x,
                       src, dst, table, bm, partial, E, eper, n_nodes);
    hipLaunchKernelGGL(k4_finish, dim3((N_OUT / 4 + 255) / 256), dim3(256), 0,
                       stream, (const float4*)v, gamma, (const float4*)partial,
                       (float4*)out, N_OUT / 4, S_eff);
  } else {
    hipLaunchKernelGGL(k0_init, dim3((n_out + 255) / 256), dim3(256), 0,
                       stream, v, gamma, out, n_out);
    hipLaunchKernelGGL(k3_direct, dim3((E + 255) / 256), dim3(256), 0, stream,
                       x, src, dst, table, bm, out, E);
  }
}

// Round 4
// 90.888 us; speedup vs baseline: 1.2283x; 1.1188x over previous
//
#include <hip/hip_runtime.h>
#include <math.h>

// force = MLP(|dr|) is piecewise-linear in the scalar edge length -> dense
// fp32 table of force(d) on [0, R]; edge pass = gather + lerp + scatter.
//
// Scatter without global atomics (memory-side on gfx950, 18.8 G/s ceiling):
// node ranges of 4096 with LDS float2 accumulators; block (r,s) scans edge
// slice s. Round-4 fix: the range filter left ~5/64 lanes doing the full
// edge math (13x dense work at 8% lane efficiency). Now: cheap ballot-
// compaction of matching edge indices into an LDS queue, processed densely
// (all lanes active) when >4096 entries are queued.

#define M_TAB 8192
#define EPSF 1e-12f
#define N_OUT 200000
#define RANGE_N 4096
#define CHUNK 4096
#define QCAP 8191
#define FLUSH_T 4095
#define S_MAX 24
#define NBM 128

#define WS_BM_OFF 0
#define WS_TABLE_OFF 1024
#define WS_PART_OFF 65536

// K1: per-block max of ||x_i||^2 -> bm[blockIdx.x].
__global__ __launch_bounds__(256) void k1_maxnorm(const float* __restrict__ x,
                                                  float* __restrict__ bm,
                                                  int n) {
  __shared__ float red[256];
  int tid = threadIdx.x;
  float m = 0.f;
  for (int i = blockIdx.x * blockDim.x + tid; i < n;
       i += gridDim.x * blockDim.x) {
    float2 p = ((const float2*)x)[i];
    m = fmaxf(m, fmaf(p.x, p.x, p.y * p.y));
  }
  red[tid] = m;
  __syncthreads();
  for (int s = 128; s > 0; s >>= 1) {
    if (tid < s) red[tid] = fmaxf(red[tid], red[tid + s]);
    __syncthreads();
  }
  if (tid == 0) bm[blockIdx.x] = red[0];
}

// K2: table[i] = MLP(i * R/(M_TAB-1)) in exact fp32.
__global__ __launch_bounds__(128) void k2_table(
    const float* __restrict__ W0, const float* __restrict__ b0,
    const float* __restrict__ W1, const float* __restrict__ b1,
    const float* __restrict__ W2, const float* __restrict__ b2,
    const float* __restrict__ W3, const float* __restrict__ b3,
    const float* __restrict__ bm, float* __restrict__ table) {
  __shared__ float bufA[128 * 8];
  __shared__ float bufB[128 * 8];
  const int j = threadIdx.x;

  bufA[j] = bm[j];
  __syncthreads();
  for (int st = 64; st > 0; st >>= 1) {
    if (j < st) bufA[j] = fmaxf(bufA[j], bufA[j + st]);
    __syncthreads();
  }
  const float R = fmaxf(2.f * sqrtf(bufA[0]), 1e-20f);
  __syncthreads();

  const float step = R / (float)(M_TAB - 1);
  const int base = blockIdx.x * 8;

  {
    float w = W0[j], b = b0[j];
#pragma unroll
    for (int p = 0; p < 8; ++p)
      bufA[j * 8 + p] = fmaxf(fmaf((float)(base + p) * step, w, b), 0.f);
  }
  __syncthreads();

  float acc[8];
  {
    float b = b1[j];
#pragma unroll
    for (int p = 0; p < 8; ++p) acc[p] = b;
#pragma unroll 8
    for (int k = 0; k < 128; ++k) {
      float w = W1[k * 128 + j];
      float4 h0 = *(const float4*)&bufA[k * 8];
      float4 h1 = *(const float4*)&bufA[k * 8 + 4];
      acc[0] = fmaf(h0.x, w, acc[0]);
      acc[1] = fmaf(h0.y, w, acc[1]);
      acc[2] = fmaf(h0.z, w, acc[2]);
      acc[3] = fmaf(h0.w, w, acc[3]);
      acc[4] = fmaf(h1.x, w, acc[4]);
      acc[5] = fmaf(h1.y, w, acc[5]);
      acc[6] = fmaf(h1.z, w, acc[6]);
      acc[7] = fmaf(h1.w, w, acc[7]);
    }
#pragma unroll
    for (int p = 0; p < 8; ++p) bufB[j * 8 + p] = fmaxf(acc[p], 0.f);
  }
  __syncthreads();

  {
    float b = b2[j];
#pragma unroll
    for (int p = 0; p < 8; ++p) acc[p] = b;
#pragma unroll 8
    for (int k = 0; k < 128; ++k) {
      float w = W2[k * 128 + j];
      float4 h0 = *(const float4*)&bufB[k * 8];
      float4 h1 = *(const float4*)&bufB[k * 8 + 4];
      acc[0] = fmaf(h0.x, w, acc[0]);
      acc[1] = fmaf(h0.y, w, acc[1]);
      acc[2] = fmaf(h0.z, w, acc[2]);
      acc[3] = fmaf(h0.w, w, acc[3]);
      acc[4] = fmaf(h1.x, w, acc[4]);
      acc[5] = fmaf(h1.y, w, acc[5]);
      acc[6] = fmaf(h1.z, w, acc[6]);
      acc[7] = fmaf(h1.w, w, acc[7]);
    }
    float w3 = W3[j];
#pragma unroll
    for (int p = 0; p < 8; ++p) bufA[j * 8 + p] = fmaxf(acc[p], 0.f) * w3;
  }
  __syncthreads();

  for (int s = 64; s > 0; s >>= 1) {
    if (j < s) {
#pragma unroll
      for (int p = 0; p < 8; ++p) bufA[j * 8 + p] += bufA[(j + s) * 8 + p];
    }
    __syncthreads();
  }
  if (j < 8) table[base + j] = bufA[j] + b3[0];
}

__device__ __forceinline__ void edge_msg(const float* __restrict__ x,
                                         const float* __restrict__ table,
                                         float inv_step, int s, int t,
                                         float& vx, float& vy) {
  float2 xs = ((const float2*)x)[s];
  float2 xt = ((const float2*)x)[t];
  float dx = xt.x - xs.x, dy = xt.y - xs.y;
  float d = sqrtf(fmaf(dx, dx, dy * dy));
  float u = fminf(d * inv_step, (float)(M_TAB - 1));
  int i0 = (int)u;
  if (i0 > M_TAB - 2) i0 = M_TAB - 2;
  float frac = u - (float)i0;
  float f0 = table[i0], f1 = table[i0 + 1];
  float f = fmaf(frac, f1 - f0, f0);
  float sc = f / fmaxf(d, EPSF);
  vx = sc * dx;
  vy = sc * dy;
}

// K3: block (r,s): ballot-compact edges with dst in range r from slice s
// into an LDS queue; process queue densely; plain-store partial copy s.
__global__ __launch_bounds__(512) void k3_ranges(
    const float* __restrict__ x, const int* __restrict__ src,
    const int* __restrict__ dst, const float* __restrict__ table,
    const float* __restrict__ bm, float* __restrict__ partial, int E,
    int eper, int n_nodes, int n_out) {
  __shared__ float acc[RANGE_N * 2];  // 32 KB
  __shared__ int queue[QCAP];         // 32 KB - 4
  __shared__ int qcount;
  const int tid = threadIdx.x;
  const int r = blockIdx.x;
  const int s = blockIdx.y;

  // R from block maxes (acc[0..127] as scratch).
  if (tid < NBM) acc[tid] = bm[tid];
  __syncthreads();
  for (int st = NBM / 2; st > 0; st >>= 1) {
    if (tid < st) acc[tid] = fmaxf(acc[tid], acc[tid + st]);
    __syncthreads();
  }
  const float R = fmaxf(2.f * sqrtf(acc[0]), 1e-20f);
  const float inv_step = (float)(M_TAB - 1) / R;
  __syncthreads();

  for (int i = tid; i < RANGE_N * 2; i += 512) acc[i] = 0.f;
  if (tid == 0) qcount = 0;
  __syncthreads();

  const int node0 = r * RANGE_N;
  const int e0 = s * eper;
  const int e1 = min(E, e0 + eper);
  const int lane = tid & 63;
  const unsigned long long lt = (1ULL << lane) - 1ULL;

#define PUSH(cond, eidx)                                        \
  {                                                             \
    bool m_ = (cond);                                           \
    unsigned long long msk_ = __ballot(m_);                     \
    if (msk_) {                                                 \
      int base_ = 0;                                            \
      if (lane == 0) base_ = atomicAdd(&qcount, __popcll(msk_));\
      base_ = __shfl(base_, 0, 64);                             \
      if (m_) queue[base_ + __popcll(msk_ & lt)] = (eidx);      \
    }                                                           \
  }

#define PROCESS_QUEUE(qn)                                       \
  for (int i = tid; i < (qn); i += 512) {                       \
    int e_ = queue[i];                                          \
    int t_ = dst[e_], sv_ = src[e_];                            \
    float vx_, vy_;                                             \
    edge_msg(x, table, inv_step, sv_, t_, vx_, vy_);            \
    int loc_ = (t_ - node0) * 2;                                \
    atomicAdd(&acc[loc_], vx_);                                 \
    atomicAdd(&acc[loc_ + 1], vy_);                             \
  }

  int eb = e0;
  for (; eb + CHUNK <= e1; eb += CHUNK) {
    int4 d0 = *(const int4*)(dst + eb + tid * 8);
    int4 d1 = *(const int4*)(dst + eb + tid * 8 + 4);
    const int ebase = eb + tid * 8;
    PUSH((unsigned)(d0.x - node0) < (unsigned)RANGE_N, ebase + 0);
    PUSH((unsigned)(d0.y - node0) < (unsigned)RANGE_N, ebase + 1);
    PUSH((unsigned)(d0.z - node0) < (unsigned)RANGE_N, ebase + 2);
    PUSH((unsigned)(d0.w - node0) < (unsigned)RANGE_N, ebase + 3);
    PUSH((unsigned)(d1.x - node0) < (unsigned)RANGE_N, ebase + 4);
    PUSH((unsigned)(d1.y - node0) < (unsigned)RANGE_N, ebase + 5);
    PUSH((unsigned)(d1.z - node0) < (unsigned)RANGE_N, ebase + 6);
    PUSH((unsigned)(d1.w - node0) < (unsigned)RANGE_N, ebase + 7);
    __syncthreads();
    int qn = qcount;
    if (qn > FLUSH_T) {
      PROCESS_QUEUE(qn);
      __syncthreads();
      if (tid == 0) qcount = 0;
      __syncthreads();
    }
  }
  // Tail: uniform trip count so ballots/leader stay wave-coherent.
  for (int ebase = eb; ebase < e1; ebase += 512) {
    int e = ebase + tid;
    bool valid = (e < e1);
    int t = valid ? dst[e] : -1;
    PUSH(valid && ((unsigned)(t - node0) < (unsigned)RANGE_N), e);
  }
  __syncthreads();
  {
    int qn = qcount;
    PROCESS_QUEUE(qn);
  }
  __syncthreads();
#undef PUSH
#undef PROCESS_QUEUE

  // Plain-store the owned range of partial copy s (float2).
  const int cnt2 = min(RANGE_N, n_nodes - node0);  // float2 count
  float2* po2 = (float2*)(partial + (size_t)s * n_out + (size_t)node0 * 2);
  const float2* a2 = (const float2*)acc;
  for (int i = tid; i < cnt2; i += 512) po2[i] = a2[i];
}

// K3 fallback: direct device-scope atomics (tiny d_ws only).
__global__ __launch_bounds__(256) void k3_direct(
    const float* __restrict__ x, const int* __restrict__ src,
    const int* __restrict__ dst, const float* __restrict__ table,
    const float* __restrict__ bm, float* __restrict__ out, int E) {
  __shared__ float red[NBM];
  int tid = threadIdx.x;
  if (tid < NBM) red[tid] = bm[tid];
  __syncthreads();
  for (int st = NBM / 2; st > 0; st >>= 1) {
    if (tid < st) red[tid] = fmaxf(red[tid], red[tid + st]);
    __syncthreads();
  }
  float R = fmaxf(2.f * sqrtf(red[0]), 1e-20f);
  float inv_step = (float)(M_TAB - 1) / R;
  int e = blockIdx.x * blockDim.x + tid;
  if (e >= E) return;
  int s = src[e], t = dst[e];
  float vx, vy;
  edge_msg(x, table, inv_step, s, t, vx, vy);
  atomicAdd(&out[2 * t + 0], vx);
  atomicAdd(&out[2 * t + 1], vy);
}

// K0 (fallback only): out = -gamma*v.
__global__ __launch_bounds__(256) void k0_init(const float* __restrict__ v,
                                               const float* __restrict__ gamma,
                                               float* __restrict__ out,
                                               int n) {
  int i = blockIdx.x * blockDim.x + threadIdx.x;
  if (i < n) out[i] = -gamma[0] * v[i];
}

// K4: out = -gamma*v + sum_{s<S} partial[s].
__global__ __launch_bounds__(256) void k4_finish(
    const float4* __restrict__ v4, const float* __restrict__ gamma,
    const float4* __restrict__ part4, float4* __restrict__ out4, int n4,
    int S) {
  int i = blockIdx.x * blockDim.x + threadIdx.x;
  if (i >= n4) return;
  float g = -gamma[0];
  float4 a = v4[i];
  float4 acc = make_float4(g * a.x, g * a.y, g * a.z, g * a.w);
  for (int c = 0; c < S; ++c) {
    float4 p = part4[(size_t)c * (N_OUT / 4) + i];
    acc.x += p.x;
    acc.y += p.y;
    acc.z += p.z;
    acc.w += p.w;
  }
  out4[i] = acc;
}

extern "C" void kernel_launch(void* const* d_in, const int* in_sizes, int n_in,
                              void* d_out, int out_size, void* d_ws,
                              size_t ws_size, hipStream_t stream) {
  const float* x = (const float*)d_in[0];
  const float* v = (const float*)d_in[1];
  const int* src = (const int*)d_in[2];
  const int* dst = (const int*)d_in[3];
  const float* gamma = (const float*)d_in[4];
  const float* W0 = (const float*)d_in[5];
  const float* b0 = (const float*)d_in[6];
  const float* W1 = (const float*)d_in[7];
  const float* b1 = (const float*)d_in[8];
  const float* W2 = (const float*)d_in[9];
  const float* b2 = (const float*)d_in[10];
  const float* W3 = (const float*)d_in[11];
  const float* b3 = (const float*)d_in[12];
  float* out = (float*)d_out;
  float* bm = (float*)((char*)d_ws + WS_BM_OFF);
  float* table = (float*)((char*)d_ws + WS_TABLE_OFF);
  float* partial = (float*)((char*)d_ws + WS_PART_OFF);

  int n_out = out_size;           // 200000
  int n_nodes = in_sizes[0] / 2;  // 100000
  int E = in_sizes[2];            // 800000

  size_t avail = ws_size > WS_PART_OFF ? ws_size - WS_PART_OFF : 0;
  int S = (int)(avail / ((size_t)N_OUT * 4));
  if (S > S_MAX) S = S_MAX;
  bool fast = (S >= 1) && (n_out == N_OUT);

  hipLaunchKernelGGL(k1_maxnorm, dim3(NBM), dim3(256), 0, stream, x, bm,
                     n_nodes);
  hipLaunchKernelGGL(k2_table, dim3(M_TAB / 8), dim3(128), 0, stream, W0, b0,
                     W1, b1, W2, b2, W3, b3, bm, table);
  if (fast) {
    int eper = ((E + S - 1) / S + CHUNK - 1) & ~(CHUNK - 1);
    int S_eff = (E + eper - 1) / eper;  // <= S
    int NR = (n_nodes + RANGE_N - 1) / RANGE_N;
    hipLaunchKernelGGL(k3_ranges, dim3(NR, S_eff), dim3(512), 0, stream, x,
                       src, dst, table, bm, partial, E, eper, n_nodes, n_out);
    hipLaunchKernelGGL(k4_finish, dim3((N_OUT / 4 + 255) / 256), dim3(256), 0,
                       stream, (const float4*)v, gamma, (const float4*)partial,
                       (float4*)out, N_OUT / 4, S_eff);
  } else {
    hipLaunchKernelGGL(k0_init, dim3((n_out + 255) / 256), dim3(256), 0,
                       stream, v, gamma, out, n_out);
    hipLaunchKernelGGL(k3_direct, dim3((E + 255) / 256), dim3(256), 0, stream,
                       x, src, dst, table, bm, out, E);
  }
}

// Round 5
// 84.498 us; speedup vs baseline: 1.3212x; 1.0756x over previous
//
#include <hip/hip_runtime.h>
#include <math.h>

// force = MLP(|dr|) is piecewise-linear in the scalar edge length -> dense
// fp32 table of force(d) on [0, R]; per-edge work = gather + lerp.
//
// Scatter without global atomics (memory-side on gfx950, 18.8 G/s ceiling):
// Round-5 structure: (k3a) ONE dense pass computes msg[e]=(vx,vy) for every
// edge, coalesced. (k3b) range-partitioned scatter: block (r,s) scans dst
// slice s; a matching edge costs only a predicated 8-B msg gather + 2 LDS
// ds_add_f32; a non-matching position costs one compare. slice = bid&7 so
// all range-blocks of a slice share one XCD's L2 (dispatch round-robin).

#define M_TAB 4096
#define EPSF 1e-12f
#define N_OUT 200000
#define RANGE_N 4096
#define S_SL 8
#define NBM 128

#define WS_BM_OFF 0
#define WS_TABLE_OFF 1024
#define WS_PART_OFF 65536
#define WS_MSG_OFF (WS_PART_OFF + (size_t)S_SL * N_OUT * 4)

// K1: per-block max of ||x_i||^2 -> bm[blockIdx.x].
__global__ __launch_bounds__(256) void k1_maxnorm(const float* __restrict__ x,
                                                  float* __restrict__ bm,
                                                  int n) {
  __shared__ float red[256];
  int tid = threadIdx.x;
  float m = 0.f;
  for (int i = blockIdx.x * blockDim.x + tid; i < n;
       i += gridDim.x * blockDim.x) {
    float2 p = ((const float2*)x)[i];
    m = fmaxf(m, fmaf(p.x, p.x, p.y * p.y));
  }
  red[tid] = m;
  __syncthreads();
  for (int s = 128; s > 0; s >>= 1) {
    if (tid < s) red[tid] = fmaxf(red[tid], red[tid + s]);
    __syncthreads();
  }
  if (tid == 0) bm[blockIdx.x] = red[0];
}

// K2: table[i] = MLP(i * R/(M_TAB-1)) in exact fp32. Thread j = neuron j,
// 8 grid points per block; h vectors broadcast from LDS (uniform address).
__global__ __launch_bounds__(128) void k2_table(
    const float* __restrict__ W0, const float* __restrict__ b0,
    const float* __restrict__ W1, const float* __restrict__ b1,
    const float* __restrict__ W2, const float* __restrict__ b2,
    const float* __restrict__ W3, const float* __restrict__ b3,
    const float* __restrict__ bm, float* __restrict__ table) {
  __shared__ float bufA[128 * 8];
  __shared__ float bufB[128 * 8];
  const int j = threadIdx.x;

  bufA[j] = bm[j];
  __syncthreads();
  for (int st = 64; st > 0; st >>= 1) {
    if (j < st) bufA[j] = fmaxf(bufA[j], bufA[j + st]);
    __syncthreads();
  }
  const float R = fmaxf(2.f * sqrtf(bufA[0]), 1e-20f);
  __syncthreads();

  const float step = R / (float)(M_TAB - 1);
  const int base = blockIdx.x * 8;

  {
    float w = W0[j], b = b0[j];
#pragma unroll
    for (int p = 0; p < 8; ++p)
      bufA[j * 8 + p] = fmaxf(fmaf((float)(base + p) * step, w, b), 0.f);
  }
  __syncthreads();

  float acc[8];
  {
    float b = b1[j];
#pragma unroll
    for (int p = 0; p < 8; ++p) acc[p] = b;
#pragma unroll 8
    for (int k = 0; k < 128; ++k) {
      float w = W1[k * 128 + j];
      float4 h0 = *(const float4*)&bufA[k * 8];
      float4 h1 = *(const float4*)&bufA[k * 8 + 4];
      acc[0] = fmaf(h0.x, w, acc[0]);
      acc[1] = fmaf(h0.y, w, acc[1]);
      acc[2] = fmaf(h0.z, w, acc[2]);
      acc[3] = fmaf(h0.w, w, acc[3]);
      acc[4] = fmaf(h1.x, w, acc[4]);
      acc[5] = fmaf(h1.y, w, acc[5]);
      acc[6] = fmaf(h1.z, w, acc[6]);
      acc[7] = fmaf(h1.w, w, acc[7]);
    }
#pragma unroll
    for (int p = 0; p < 8; ++p) bufB[j * 8 + p] = fmaxf(acc[p], 0.f);
  }
  __syncthreads();

  {
    float b = b2[j];
#pragma unroll
    for (int p = 0; p < 8; ++p) acc[p] = b;
#pragma unroll 8
    for (int k = 0; k < 128; ++k) {
      float w = W2[k * 128 + j];
      float4 h0 = *(const float4*)&bufB[k * 8];
      float4 h1 = *(const float4*)&bufB[k * 8 + 4];
      acc[0] = fmaf(h0.x, w, acc[0]);
      acc[1] = fmaf(h0.y, w, acc[1]);
      acc[2] = fmaf(h0.z, w, acc[2]);
      acc[3] = fmaf(h0.w, w, acc[3]);
      acc[4] = fmaf(h1.x, w, acc[4]);
      acc[5] = fmaf(h1.y, w, acc[5]);
      acc[6] = fmaf(h1.z, w, acc[6]);
      acc[7] = fmaf(h1.w, w, acc[7]);
    }
    float w3 = W3[j];
#pragma unroll
    for (int p = 0; p < 8; ++p) bufA[j * 8 + p] = fmaxf(acc[p], 0.f) * w3;
  }
  __syncthreads();

  for (int s = 64; s > 0; s >>= 1) {
    if (j < s) {
#pragma unroll
      for (int p = 0; p < 8; ++p) bufA[j * 8 + p] += bufA[(j + s) * 8 + p];
    }
    __syncthreads();
  }
  if (j < 8) table[base + j] = bufA[j] + b3[0];
}

__device__ __forceinline__ void edge_msg(const float* __restrict__ x,
                                         const float* __restrict__ table,
                                         float inv_step, int s, int t,
                                         float& vx, float& vy) {
  float2 xs = ((const float2*)x)[s];
  float2 xt = ((const float2*)x)[t];
  float dx = xt.x - xs.x, dy = xt.y - xs.y;
  float d = sqrtf(fmaf(dx, dx, dy * dy));
  float u = fminf(d * inv_step, (float)(M_TAB - 1));
  int i0 = (int)u;
  if (i0 > M_TAB - 2) i0 = M_TAB - 2;
  float frac = u - (float)i0;
  float f0 = table[i0], f1 = table[i0 + 1];
  float f = fmaf(frac, f1 - f0, f0);
  float sc = f / fmaxf(d, EPSF);
  vx = sc * dx;
  vy = sc * dy;
}

// K3a: dense message pass — msg[e] = (vx,vy) for every edge, coalesced.
__global__ __launch_bounds__(256) void k3a_msg(
    const float* __restrict__ x, const int* __restrict__ src,
    const int* __restrict__ dst, const float* __restrict__ table,
    const float* __restrict__ bm, float2* __restrict__ msg, int E) {
  __shared__ float red[NBM];
  const int tid = threadIdx.x;
  if (tid < NBM) red[tid] = bm[tid];
  __syncthreads();
  for (int st = NBM / 2; st > 0; st >>= 1) {
    if (tid < st) red[tid] = fmaxf(red[tid], red[tid + st]);
    __syncthreads();
  }
  const float R = fmaxf(2.f * sqrtf(red[0]), 1e-20f);
  const float inv_step = (float)(M_TAB - 1) / R;

  const int e0 = (blockIdx.x * 256 + tid) * 4;
  if (e0 + 3 < E) {
    int4 s4 = *(const int4*)(src + e0);
    int4 d4 = *(const int4*)(dst + e0);
    float2 m0, m1, m2, m3;
    edge_msg(x, table, inv_step, s4.x, d4.x, m0.x, m0.y);
    edge_msg(x, table, inv_step, s4.y, d4.y, m1.x, m1.y);
    edge_msg(x, table, inv_step, s4.z, d4.z, m2.x, m2.y);
    edge_msg(x, table, inv_step, s4.w, d4.w, m3.x, m3.y);
    *(float4*)(msg + e0) = make_float4(m0.x, m0.y, m1.x, m1.y);
    *(float4*)(msg + e0 + 2) = make_float4(m2.x, m2.y, m3.x, m3.y);
  } else {
    for (int e = e0; e < E; ++e) {
      float2 m;
      edge_msg(x, table, inv_step, src[e], dst[e], m.x, m.y);
      msg[e] = m;
    }
  }
}

// K3b: block (r,s) with s = bid&7, r = bid>>3. Scan dst slice s; matching
// edges do a predicated msg gather + 2 LDS adds. Plain-store partial s.
__global__ __launch_bounds__(512) void k3b_scatter(
    const int* __restrict__ dst, const float2* __restrict__ msg,
    float* __restrict__ partial, int E, int eper, int n_nodes) {
  __shared__ float acc[RANGE_N * 2];  // 32 KB
  const int tid = threadIdx.x;
  const int s = blockIdx.x & (S_SL - 1);
  const int r = blockIdx.x >> 3;

  for (int i = tid; i < RANGE_N * 2; i += 512) acc[i] = 0.f;
  __syncthreads();

  const int node0 = r * RANGE_N;
  const int e0 = s * eper;
  const int e1 = min(E, e0 + eper);

#define TRY(dd, ee)                                   \
  {                                                   \
    unsigned loc_ = (unsigned)((dd)-node0);           \
    if (loc_ < (unsigned)RANGE_N) {                   \
      float2 m_ = msg[(ee)];                          \
      atomicAdd(&acc[loc_ * 2], m_.x);                \
      atomicAdd(&acc[loc_ * 2 + 1], m_.y);            \
    }                                                 \
  }

  int eb = e0;
  for (; eb + 2048 <= e1; eb += 2048) {
    const int e = eb + tid * 4;
    int4 d4 = *(const int4*)(dst + e);
    TRY(d4.x, e);
    TRY(d4.y, e + 1);
    TRY(d4.z, e + 2);
    TRY(d4.w, e + 3);
  }
  for (int e = eb + tid; e < e1; e += 512) {
    int dd = dst[e];
    TRY(dd, e);
  }
#undef TRY
  __syncthreads();

  const int cnt2 = min(RANGE_N, n_nodes - node0);
  float2* po = (float2*)(partial + (size_t)s * N_OUT) + node0;
  const float2* a2 = (const float2*)acc;
  for (int i = tid; i < cnt2; i += 512) po[i] = a2[i];
}

// K3 fallback: direct device-scope atomics (tiny d_ws only).
__global__ __launch_bounds__(256) void k3_direct(
    const float* __restrict__ x, const int* __restrict__ src,
    const int* __restrict__ dst, const float* __restrict__ table,
    const float* __restrict__ bm, float* __restrict__ out, int E) {
  __shared__ float red[NBM];
  int tid = threadIdx.x;
  if (tid < NBM) red[tid] = bm[tid];
  __syncthreads();
  for (int st = NBM / 2; st > 0; st >>= 1) {
    if (tid < st) red[tid] = fmaxf(red[tid], red[tid + st]);
    __syncthreads();
  }
  float R = fmaxf(2.f * sqrtf(red[0]), 1e-20f);
  float inv_step = (float)(M_TAB - 1) / R;
  int e = blockIdx.x * blockDim.x + tid;
  if (e >= E) return;
  int s = src[e], t = dst[e];
  float vx, vy;
  edge_msg(x, table, inv_step, s, t, vx, vy);
  atomicAdd(&out[2 * t + 0], vx);
  atomicAdd(&out[2 * t + 1], vy);
}

// K0 (fallback only): out = -gamma*v.
__global__ __launch_bounds__(256) void k0_init(const float* __restrict__ v,
                                               const float* __restrict__ gamma,
                                               float* __restrict__ out,
                                               int n) {
  int i = blockIdx.x * blockDim.x + threadIdx.x;
  if (i < n) out[i] = -gamma[0] * v[i];
}

// K4: out = -gamma*v + sum_{s<S_SL} partial[s].
__global__ __launch_bounds__(256) void k4_finish(
    const float4* __restrict__ v4, const float* __restrict__ gamma,
    const float4* __restrict__ part4, float4* __restrict__ out4, int n4) {
  int i = blockIdx.x * blockDim.x + threadIdx.x;
  if (i >= n4) return;
  float g = -gamma[0];
  float4 a = v4[i];
  float4 acc = make_float4(g * a.x, g * a.y, g * a.z, g * a.w);
#pragma unroll
  for (int c = 0; c < S_SL; ++c) {
    float4 p = part4[(size_t)c * (N_OUT / 4) + i];
    acc.x += p.x;
    acc.y += p.y;
    acc.z += p.z;
    acc.w += p.w;
  }
  out4[i] = acc;
}

extern "C" void kernel_launch(void* const* d_in, const int* in_sizes, int n_in,
                              void* d_out, int out_size, void* d_ws,
                              size_t ws_size, hipStream_t stream) {
  const float* x = (const float*)d_in[0];
  const float* v = (const float*)d_in[1];
  const int* src = (const int*)d_in[2];
  const int* dst = (const int*)d_in[3];
  const float* gamma = (const float*)d_in[4];
  const float* W0 = (const float*)d_in[5];
  const float* b0 = (const float*)d_in[6];
  const float* W1 = (const float*)d_in[7];
  const float* b1 = (const float*)d_in[8];
  const float* W2 = (const float*)d_in[9];
  const float* b2 = (const float*)d_in[10];
  const float* W3 = (const float*)d_in[11];
  const float* b3 = (const float*)d_in[12];
  float* out = (float*)d_out;
  float* bm = (float*)((char*)d_ws + WS_BM_OFF);
  float* table = (float*)((char*)d_ws + WS_TABLE_OFF);
  float* partial = (float*)((char*)d_ws + WS_PART_OFF);
  float2* msg = (float2*)((char*)d_ws + WS_MSG_OFF);

  int n_out = out_size;           // 200000
  int n_nodes = in_sizes[0] / 2;  // 100000
  int E = in_sizes[2];            // 800000

  size_t need = WS_MSG_OFF + (size_t)E * 8;
  bool fast = (ws_size >= need) && (n_out == N_OUT);

  hipLaunchKernelGGL(k1_maxnorm, dim3(NBM), dim3(256), 0, stream, x, bm,
                     n_nodes);
  hipLaunchKernelGGL(k2_table, dim3(M_TAB / 8), dim3(128), 0, stream, W0, b0,
                     W1, b1, W2, b2, W3, b3, bm, table);
  if (fast) {
    int eper = ((E + S_SL - 1) / S_SL + 3) & ~3;
    int NRG = (n_nodes + RANGE_N - 1) / RANGE_N;
    hipLaunchKernelGGL(k3a_msg, dim3((E + 1023) / 1024), dim3(256), 0, stream,
                       x, src, dst, table, bm, msg, E);
    hipLaunchKernelGGL(k3b_scatter, dim3(NRG * S_SL), dim3(512), 0, stream,
                       dst, msg, partial, E, eper, n_nodes);
    hipLaunchKernelGGL(k4_finish, dim3((N_OUT / 4 + 255) / 256), dim3(256), 0,
                       stream, (const float4*)v, gamma, (const float4*)partial,
                       (float4*)out, N_OUT / 4);
  } else {
    hipLaunchKernelGGL(k0_init, dim3((n_out + 255) / 256), dim3(256), 0,
                       stream, v, gamma, out, n_out);
    hipLaunchKernelGGL(k3_direct, dim3((E + 255) / 256), dim3(256), 0, stream,
                       x, src, dst, table, bm, out, E);
  }
}

// Round 6
// 57.584 us; speedup vs baseline: 1.9388x; 1.4674x over previous
//
#include <hip/hip_runtime.h>
#include <math.h>

// force = MLP(|dr|) is piecewise-linear in scalar edge length -> dense fp32
// table of force(d) on [0, R]; per-edge work = gather + lerp.
//
// Scatter structure (round 6): fused msg + deterministic per-block counting
// sort by dst-range (k3bin): each block owns a fixed 2048-slot bin region,
// writes its edges bucket-sorted + per-block cnt/off tables (NO global
// atomics). k3scat (range r, slice p) consumes runs of blocks b%8==p: each
// edge touched exactly once (the 25x redundant scan of rounds 3-5 is gone),
// LDS accumulate, plain-store partial copy p. k4 sums 8 partials + -gamma*v.

#define M_TAB 4096
#define EPSF 1e-12f
#define N_OUT 200000
#define RANGE_N 4096
#define RSHIFT 12
#define P_SL 8
#define NBM 128
#define BCHUNK 2048

#define WS_BM_OFF 0
#define WS_TABLE_OFF 1024

// K1: per-block max of ||x_i||^2 -> bm[blockIdx.x].
__global__ __launch_bounds__(256) void k1_maxnorm(const float* __restrict__ x,
                                                  float* __restrict__ bm,
                                                  int n) {
  __shared__ float red[256];
  int tid = threadIdx.x;
  float m = 0.f;
  for (int i = blockIdx.x * blockDim.x + tid; i < n;
       i += gridDim.x * blockDim.x) {
    float2 p = ((const float2*)x)[i];
    m = fmaxf(m, fmaf(p.x, p.x, p.y * p.y));
  }
  red[tid] = m;
  __syncthreads();
  for (int s = 128; s > 0; s >>= 1) {
    if (tid < s) red[tid] = fmaxf(red[tid], red[tid + s]);
    __syncthreads();
  }
  if (tid == 0) bm[blockIdx.x] = red[0];
}

// K2: table[i] = MLP(i * R/(M_TAB-1)) in exact fp32.
__global__ __launch_bounds__(128) void k2_table(
    const float* __restrict__ W0, const float* __restrict__ b0,
    const float* __restrict__ W1, const float* __restrict__ b1,
    const float* __restrict__ W2, const float* __restrict__ b2,
    const float* __restrict__ W3, const float* __restrict__ b3,
    const float* __restrict__ bm, float* __restrict__ table) {
  __shared__ float bufA[128 * 8];
  __shared__ float bufB[128 * 8];
  const int j = threadIdx.x;

  bufA[j] = bm[j];
  __syncthreads();
  for (int st = 64; st > 0; st >>= 1) {
    if (j < st) bufA[j] = fmaxf(bufA[j], bufA[j + st]);
    __syncthreads();
  }
  const float R = fmaxf(2.f * sqrtf(bufA[0]), 1e-20f);
  __syncthreads();

  const float step = R / (float)(M_TAB - 1);
  const int base = blockIdx.x * 8;

  {
    float w = W0[j], b = b0[j];
#pragma unroll
    for (int p = 0; p < 8; ++p)
      bufA[j * 8 + p] = fmaxf(fmaf((float)(base + p) * step, w, b), 0.f);
  }
  __syncthreads();

  float acc[8];
  {
    float b = b1[j];
#pragma unroll
    for (int p = 0; p < 8; ++p) acc[p] = b;
#pragma unroll 8
    for (int k = 0; k < 128; ++k) {
      float w = W1[k * 128 + j];
      float4 h0 = *(const float4*)&bufA[k * 8];
      float4 h1 = *(const float4*)&bufA[k * 8 + 4];
      acc[0] = fmaf(h0.x, w, acc[0]);
      acc[1] = fmaf(h0.y, w, acc[1]);
      acc[2] = fmaf(h0.z, w, acc[2]);
      acc[3] = fmaf(h0.w, w, acc[3]);
      acc[4] = fmaf(h1.x, w, acc[4]);
      acc[5] = fmaf(h1.y, w, acc[5]);
      acc[6] = fmaf(h1.z, w, acc[6]);
      acc[7] = fmaf(h1.w, w, acc[7]);
    }
#pragma unroll
    for (int p = 0; p < 8; ++p) bufB[j * 8 + p] = fmaxf(acc[p], 0.f);
  }
  __syncthreads();

  {
    float b = b2[j];
#pragma unroll
    for (int p = 0; p < 8; ++p) acc[p] = b;
#pragma unroll 8
    for (int k = 0; k < 128; ++k) {
      float w = W2[k * 128 + j];
      float4 h0 = *(const float4*)&bufB[k * 8];
      float4 h1 = *(const float4*)&bufB[k * 8 + 4];
      acc[0] = fmaf(h0.x, w, acc[0]);
      acc[1] = fmaf(h0.y, w, acc[1]);
      acc[2] = fmaf(h0.z, w, acc[2]);
      acc[3] = fmaf(h0.w, w, acc[3]);
      acc[4] = fmaf(h1.x, w, acc[4]);
      acc[5] = fmaf(h1.y, w, acc[5]);
      acc[6] = fmaf(h1.z, w, acc[6]);
      acc[7] = fmaf(h1.w, w, acc[7]);
    }
    float w3 = W3[j];
#pragma unroll
    for (int p = 0; p < 8; ++p) bufA[j * 8 + p] = fmaxf(acc[p], 0.f) * w3;
  }
  __syncthreads();

  for (int s = 64; s > 0; s >>= 1) {
    if (j < s) {
#pragma unroll
      for (int p = 0; p < 8; ++p) bufA[j * 8 + p] += bufA[(j + s) * 8 + p];
    }
    __syncthreads();
  }
  if (j < 8) table[base + j] = bufA[j] + b3[0];
}

__device__ __forceinline__ void edge_msg(const float* __restrict__ x,
                                         const float* __restrict__ table,
                                         float inv_step, int s, int t,
                                         float& vx, float& vy) {
  float2 xs = ((const float2*)x)[s];
  float2 xt = ((const float2*)x)[t];
  float dx = xt.x - xs.x, dy = xt.y - xs.y;
  float d = sqrtf(fmaf(dx, dx, dy * dy));
  float u = fminf(d * inv_step, (float)(M_TAB - 1));
  int i0 = (int)u;
  if (i0 > M_TAB - 2) i0 = M_TAB - 2;
  float frac = u - (float)i0;
  float f0 = table[i0], f1 = table[i0 + 1];
  float f = fmaf(frac, f1 - f0, f0);
  float sc = f / fmaxf(d, EPSF);
  vx = sc * dx;
  vy = sc * dy;
}

// K3bin: block b owns edges [b*2048, b*2048+2048) and bin region
// [b*2048, ...). Compute msg, bucket-sort into own region, write cnt/off.
__global__ __launch_bounds__(256) void k3bin(
    const float* __restrict__ x, const int* __restrict__ src,
    const int* __restrict__ dst, const float* __restrict__ table,
    const float* __restrict__ bm, int* __restrict__ binDst,
    float2* __restrict__ binMsg, int* __restrict__ cntTab,
    int* __restrict__ offTab, int E) {
  __shared__ float red[NBM];
  __shared__ int cntL[32];
  __shared__ int offL[32];
  const int tid = threadIdx.x;

  if (tid < NBM) red[tid] = bm[tid];
  if (tid < 32) cntL[tid] = 0;
  __syncthreads();
  for (int st = NBM / 2; st > 0; st >>= 1) {
    if (tid < st) red[tid] = fmaxf(red[tid], red[tid + st]);
    __syncthreads();
  }
  const float R = fmaxf(2.f * sqrtf(red[0]), 1e-20f);
  const float inv_step = (float)(M_TAB - 1) / R;

  const int e0 = blockIdx.x * BCHUNK + tid * 8;
  int msrc[8], mdst[8], mrank[8];
  float mvx[8], mvy[8];
  if (e0 + 7 < E) {
    int4 a = *(const int4*)(src + e0);
    int4 b4 = *(const int4*)(src + e0 + 4);
    int4 c = *(const int4*)(dst + e0);
    int4 d4 = *(const int4*)(dst + e0 + 4);
    msrc[0] = a.x; msrc[1] = a.y; msrc[2] = a.z; msrc[3] = a.w;
    msrc[4] = b4.x; msrc[5] = b4.y; msrc[6] = b4.z; msrc[7] = b4.w;
    mdst[0] = c.x; mdst[1] = c.y; mdst[2] = c.z; mdst[3] = c.w;
    mdst[4] = d4.x; mdst[5] = d4.y; mdst[6] = d4.z; mdst[7] = d4.w;
  } else {
#pragma unroll
    for (int i = 0; i < 8; ++i) {
      bool v = (e0 + i < E);
      msrc[i] = v ? src[e0 + i] : 0;
      mdst[i] = v ? dst[e0 + i] : -1;
    }
  }
#pragma unroll
  for (int i = 0; i < 8; ++i) {
    if (mdst[i] >= 0) {
      mrank[i] = atomicAdd(&cntL[mdst[i] >> RSHIFT], 1);
      edge_msg(x, table, inv_step, msrc[i], mdst[i], mvx[i], mvy[i]);
    }
  }
  __syncthreads();
  if (tid == 0) {
    int s = 0;
#pragma unroll
    for (int k = 0; k < 32; ++k) {
      offL[k] = s;
      s += cntL[k];
    }
  }
  __syncthreads();
  if (tid < 32) {
    cntTab[blockIdx.x * 32 + tid] = cntL[tid];
    offTab[blockIdx.x * 32 + tid] = offL[tid];
  }
  const int rbase = blockIdx.x * BCHUNK;
#pragma unroll
  for (int i = 0; i < 8; ++i) {
    if (mdst[i] >= 0) {
      int pos = rbase + offL[mdst[i] >> RSHIFT] + mrank[i];
      binDst[pos] = mdst[i] & (RANGE_N - 1);
      binMsg[pos] = make_float2(mvx[i], mvy[i]);
    }
  }
}

// K3scat: block (r = bid>>3, p = bid&7): consume runs of binning blocks
// b % 8 == p for bucket r; LDS accumulate; plain-store partial copy p.
__global__ __launch_bounds__(512) void k3scat(
    const int* __restrict__ binDst, const float2* __restrict__ binMsg,
    const int* __restrict__ cntTab, const int* __restrict__ offTab,
    float* __restrict__ partial, int NB, int n_nodes) {
  __shared__ float acc[RANGE_N * 2];  // 32 KB
  __shared__ int runBase[64];
  __shared__ int runLen[64];
  const int tid = threadIdx.x;
  const int p = blockIdx.x & (P_SL - 1);
  const int r = blockIdx.x >> 3;

  for (int i = tid; i < RANGE_N * 2; i += 512) acc[i] = 0.f;
  const int nrun = (NB - p + P_SL - 1) / P_SL;
  for (int j = tid; j < nrun; j += 512) {
    int b = p + j * P_SL;
    runBase[j] = b * BCHUNK + offTab[b * 32 + r];
    runLen[j] = cntTab[b * 32 + r];
  }
  __syncthreads();

  const int w = tid >> 6, lane = tid & 63;
  for (int j = w; j < nrun; j += 8) {
    int base = runBase[j], len = runLen[j];
    for (int i = lane; i < len; i += 64) {
      int dd = binDst[base + i];
      float2 m = binMsg[base + i];
      atomicAdd(&acc[dd * 2], m.x);
      atomicAdd(&acc[dd * 2 + 1], m.y);
    }
  }
  __syncthreads();

  const int node0 = r * RANGE_N;
  const int cnt2 = min(RANGE_N, n_nodes - node0);
  float2* po = (float2*)(partial + (size_t)p * N_OUT) + node0;
  const float2* a2 = (const float2*)acc;
  for (int i = tid; i < cnt2; i += 512) po[i] = a2[i];
}

// K3 fallback: direct device-scope atomics (tiny d_ws only).
__global__ __launch_bounds__(256) void k3_direct(
    const float* __restrict__ x, const int* __restrict__ src,
    const int* __restrict__ dst, const float* __restrict__ table,
    const float* __restrict__ bm, float* __restrict__ out, int E) {
  __shared__ float red[NBM];
  int tid = threadIdx.x;
  if (tid < NBM) red[tid] = bm[tid];
  __syncthreads();
  for (int st = NBM / 2; st > 0; st >>= 1) {
    if (tid < st) red[tid] = fmaxf(red[tid], red[tid + st]);
    __syncthreads();
  }
  float R = fmaxf(2.f * sqrtf(red[0]), 1e-20f);
  float inv_step = (float)(M_TAB - 1) / R;
  int e = blockIdx.x * blockDim.x + tid;
  if (e >= E) return;
  int s = src[e], t = dst[e];
  float vx, vy;
  edge_msg(x, table, inv_step, s, t, vx, vy);
  atomicAdd(&out[2 * t + 0], vx);
  atomicAdd(&out[2 * t + 1], vy);
}

// K0 (fallback only): out = -gamma*v.
__global__ __launch_bounds__(256) void k0_init(const float* __restrict__ v,
                                               const float* __restrict__ gamma,
                                               float* __restrict__ out,
                                               int n) {
  int i = blockIdx.x * blockDim.x + threadIdx.x;
  if (i < n) out[i] = -gamma[0] * v[i];
}

// K4: out = -gamma*v + sum_{p<8} partial[p].
__global__ __launch_bounds__(256) void k4_finish(
    const float4* __restrict__ v4, const float* __restrict__ gamma,
    const float4* __restrict__ part4, float4* __restrict__ out4, int n4) {
  int i = blockIdx.x * blockDim.x + threadIdx.x;
  if (i >= n4) return;
  float g = -gamma[0];
  float4 a = v4[i];
  float4 acc = make_float4(g * a.x, g * a.y, g * a.z, g * a.w);
#pragma unroll
  for (int c = 0; c < P_SL; ++c) {
    float4 p = part4[(size_t)c * (N_OUT / 4) + i];
    acc.x += p.x;
    acc.y += p.y;
    acc.z += p.z;
    acc.w += p.w;
  }
  out4[i] = acc;
}

extern "C" void kernel_launch(void* const* d_in, const int* in_sizes, int n_in,
                              void* d_out, int out_size, void* d_ws,
                              size_t ws_size, hipStream_t stream) {
  const float* x = (const float*)d_in[0];
  const float* v = (const float*)d_in[1];
  const int* src = (const int*)d_in[2];
  const int* dst = (const int*)d_in[3];
  const float* gamma = (const float*)d_in[4];
  const float* W0 = (const float*)d_in[5];
  const float* b0 = (const float*)d_in[6];
  const float* W1 = (const float*)d_in[7];
  const float* b1 = (const float*)d_in[8];
  const float* W2 = (const float*)d_in[9];
  const float* b2 = (const float*)d_in[10];
  const float* W3 = (const float*)d_in[11];
  const float* b3 = (const float*)d_in[12];
  float* out = (float*)d_out;
  float* bm = (float*)((char*)d_ws + WS_BM_OFF);
  float* table = (float*)((char*)d_ws + WS_TABLE_OFF);

  int n_out = out_size;           // 200000
  int n_nodes = in_sizes[0] / 2;  // 100000
  int E = in_sizes[2];            // 800000

  const int NB = (E + BCHUNK - 1) / BCHUNK;
  size_t sz_tab = ((size_t)NB * 32 * 4 + 255) & ~(size_t)255;
  size_t off_cnt = 65536;
  size_t off_off = off_cnt + sz_tab;
  size_t off_part = off_off + sz_tab;
  size_t off_bdst = off_part + (size_t)P_SL * N_OUT * 4;
  size_t off_bmsg = off_bdst + (size_t)NB * BCHUNK * 4;
  size_t need = off_bmsg + (size_t)NB * BCHUNK * 8;

  int NR = (n_nodes + RANGE_N - 1) / RANGE_N;
  bool fast = (ws_size >= need) && (n_out == N_OUT) && (NR <= 32) &&
              (n_nodes <= N_OUT / 2);

  hipLaunchKernelGGL(k1_maxnorm, dim3(NBM), dim3(256), 0, stream, x, bm,
                     n_nodes);
  hipLaunchKernelGGL(k2_table, dim3(M_TAB / 8), dim3(128), 0, stream, W0, b0,
                     W1, b1, W2, b2, W3, b3, bm, table);
  if (fast) {
    int* cntTab = (int*)((char*)d_ws + off_cnt);
    int* offTab = (int*)((char*)d_ws + off_off);
    float* partial = (float*)((char*)d_ws + off_part);
    int* binDst = (int*)((char*)d_ws + off_bdst);
    float2* binMsg = (float2*)((char*)d_ws + off_bmsg);
    hipLaunchKernelGGL(k3bin, dim3(NB), dim3(256), 0, stream, x, src, dst,
                       table, bm, binDst, binMsg, cntTab, offTab, E);
    hipLaunchKernelGGL(k3scat, dim3(NR * P_SL), dim3(512), 0, stream, binDst,
                       binMsg, cntTab, offTab, partial, NB, n_nodes);
    hipLaunchKernelGGL(k4_finish, dim3((N_OUT / 4 + 255) / 256), dim3(256), 0,
                       stream, (const float4*)v, gamma, (const float4*)partial,
                       (float4*)out, N_OUT / 4);
  } else {
    hipLaunchKernelGGL(k0_init, dim3((n_out + 255) / 256), dim3(256), 0,
                       stream, v, gamma, out, n_out);
    hipLaunchKernelGGL(k3_direct, dim3((E + 255) / 256), dim3(256), 0, stream,
                       x, src, dst, table, bm, out, E);
  }
}